// Round 7
// baseline (542.998 us; speedup 1.0000x reference)
//
#include <hip/hip_runtime.h>

typedef unsigned short u16t;
typedef __bf16 bf16x8 __attribute__((ext_vector_type(8)));
typedef float f32x4 __attribute__((ext_vector_type(4)));

#define NB 4
#define NS 2048
#define ND 1024
#define NH 16
#define NDK 64
#define NEGINF -1.0e9f
// softmax runs in exp2 domain: SCALE2 = 0.125 * log2(e)
#define SCALE2 0.18033688011112042f

// padded LDS row stride for gemm (32-wide tiles): 40 elem = 80B, 5 granules,
// coprime with 8 -> conflict-free frag reads.
#define LAB 40

__device__ __forceinline__ float fexp2(float x) { return __builtin_amdgcn_exp2f(x); }

// native bf16 convert (RNE via v_cvt_pk_bf16_f32; 1 inst vs 3 bit-ops)
__device__ __forceinline__ u16t f2bf(float f) {
  return __builtin_bit_cast(u16t, (__bf16)f);
}

// DPP rotate within 16-lane rows (softmax reduce: VALU pipe, ~3 cyc/step vs
// ~35 cyc ds_bpermute for shfl). Correctness verified R2/R5/R6.
#define ROR16(x, n) __builtin_bit_cast(float, __builtin_amdgcn_update_dpp(     \
    __builtin_bit_cast(int, (x)), __builtin_bit_cast(int, (x)),                \
    0x120 + (n), 0xF, 0xF, false))

// XOR-swizzle index for [*][64] u16 tiles: rotates 16B granules within each
// 8-row stripe -> conflict-free b128 reads at 128B row stride (no padding).
// Verified: SQ_LDS_BANK_CONFLICT == 0 since R2.
__device__ __forceinline__ int swz(int row, int col) {
  return row * 64 + (col ^ ((row & 7) << 3));
}

// register staging helpers (raw loads now, convert at LDS-store time)
template<typename TA> struct Stg;
template<> struct Stg<float> {
  f32x4 lo, hi;
  __device__ __forceinline__ void ld(const float* p) {
    lo = *(const f32x4*)p; hi = *(const f32x4*)(p + 4);
  }
  __device__ __forceinline__ bf16x8 get() const {
    bf16x8 r;
    r[0] = (__bf16)lo[0]; r[1] = (__bf16)lo[1]; r[2] = (__bf16)lo[2]; r[3] = (__bf16)lo[3];
    r[4] = (__bf16)hi[0]; r[5] = (__bf16)hi[1]; r[6] = (__bf16)hi[2]; r[7] = (__bf16)hi[3];
    return r;
  }
};
template<> struct Stg<u16t> {
  bf16x8 v;
  __device__ __forceinline__ void ld(const u16t* p) { v = *(const bf16x8*)p; }
  __device__ __forceinline__ bf16x8 get() const { return v; }
};

// ---------------------------------------------------------------------------
// Fused Q/K/V projection GEMM: one launch, blockIdx.z selects {Q,K,V}.
// C[M,N] = A[M,K] * W[N,K]^T ; M=8192, N=K=1024, bf16 MFMA, fp32 acc.
// z=0,1: C bf16 scatter to [B,H,S,dk] (Q,K);  z=2: [B,H,dk,S] (V transposed).
// Software-pipelined staging; 128x128 tile, BK=32, 4 waves.
// ---------------------------------------------------------------------------
__global__ __launch_bounds__(256, 2)
void qkv_proj(const float* __restrict__ Aq, const float* __restrict__ Ak,
              const float* __restrict__ Av,
              const float* __restrict__ Wq, const float* __restrict__ Wk,
              const float* __restrict__ Wv,
              u16t* __restrict__ Cq, u16t* __restrict__ Ck, u16t* __restrict__ Cvp)
{
  const int K = 1024;
  __shared__ __attribute__((aligned(16))) u16t At[128 * LAB];
  __shared__ __attribute__((aligned(16))) u16t Bt[128 * LAB];

  const int z = blockIdx.z;
  const float* A  = (z == 0) ? Aq : (z == 1) ? Ak : Av;
  const float* Bm = (z == 0) ? Wq : (z == 1) ? Wk : Wv;
  u16t* C = (z == 0) ? Cq : (z == 1) ? Ck : Cvp;

  const int tid  = threadIdx.x;
  const int w    = tid >> 6;
  const int lane = tid & 63;
  const int quad = lane >> 4;
  const int l16  = lane & 15;
  const int wm   = w >> 1, wn = w & 1;
  const int m0   = blockIdx.x * 128;
  const int n0   = blockIdx.y * 128;

  const f32x4 fz = {0.f, 0.f, 0.f, 0.f};
  f32x4 acc[4][4];
#pragma unroll
  for (int i = 0; i < 4; i++)
#pragma unroll
    for (int j = 0; j < 4; j++) acc[i][j] = fz;

  const int r0 = tid >> 2, cg = (tid & 3) * 8;
  const int r1 = r0 + 64;

  Stg<float> sa0, sa1, sb0, sb1;
  sa0.ld(A  + (long)(m0 + r0) * K + cg);
  sa1.ld(A  + (long)(m0 + r1) * K + cg);
  sb0.ld(Bm + (long)(n0 + r0) * K + cg);
  sb1.ld(Bm + (long)(n0 + r1) * K + cg);

  for (int k0 = 0; k0 < K; k0 += 32) {
    __syncthreads();
    *(bf16x8*)&At[r0 * LAB + cg] = sa0.get();
    *(bf16x8*)&At[r1 * LAB + cg] = sa1.get();
    *(bf16x8*)&Bt[r0 * LAB + cg] = sb0.get();
    *(bf16x8*)&Bt[r1 * LAB + cg] = sb1.get();
    __syncthreads();
    if (k0 + 32 < K) {
      sa0.ld(A  + (long)(m0 + r0) * K + k0 + 32 + cg);
      sa1.ld(A  + (long)(m0 + r1) * K + k0 + 32 + cg);
      sb0.ld(Bm + (long)(n0 + r0) * K + k0 + 32 + cg);
      sb1.ld(Bm + (long)(n0 + r1) * K + k0 + 32 + cg);
    }

    bf16x8 af[4], bfv[4];
#pragma unroll
    for (int i = 0; i < 4; i++)
      af[i] = *(const bf16x8*)&At[(wm * 64 + i * 16 + l16) * LAB + quad * 8];
#pragma unroll
    for (int j = 0; j < 4; j++)
      bfv[j] = *(const bf16x8*)&Bt[(wn * 64 + j * 16 + l16) * LAB + quad * 8];
#pragma unroll
    for (int i = 0; i < 4; i++)
#pragma unroll
      for (int j = 0; j < 4; j++)
        acc[i][j] = __builtin_amdgcn_mfma_f32_16x16x32_bf16(af[i], bfv[j], acc[i][j], 0, 0, 0);
  }

#pragma unroll
  for (int i = 0; i < 4; i++) {
    const int rbase = m0 + wm * 64 + i * 16 + quad * 4;
#pragma unroll
    for (int j = 0; j < 4; j++) {
      const int col = n0 + wn * 64 + j * 16 + l16;
#pragma unroll
      for (int r = 0; r < 4; r++) {
        const int row = rbase + r;
        int b = row >> 11, s = row & 2047, h = col >> 6, d = col & 63;
        if (z < 2)
          C[(((long)(b * NH + h)) * NS + s) * NDK + d] = f2bf(acc[i][j][r]);
        else
          C[(((long)(b * NH + h)) * NDK + d) * NS + s] = f2bf(acc[i][j][r]);
      }
    }
  }
}

// ---------------------------------------------------------------------------
// NT GEMM (output projection): C fp32 [M,N] = A[M,K](bf16) * W[N,K]^T + bias.
// ---------------------------------------------------------------------------
__global__ __launch_bounds__(256, 2)
void gemm_out(const u16t* __restrict__ A, const float* __restrict__ Bm,
              float* __restrict__ Cv, const float* __restrict__ bias)
{
  const int K = 1024;
  __shared__ __attribute__((aligned(16))) u16t At[128 * LAB];
  __shared__ __attribute__((aligned(16))) u16t Bt[128 * LAB];

  const int tid  = threadIdx.x;
  const int w    = tid >> 6;
  const int lane = tid & 63;
  const int quad = lane >> 4;
  const int l16  = lane & 15;
  const int wm   = w >> 1, wn = w & 1;
  const int m0   = blockIdx.x * 128;
  const int n0   = blockIdx.y * 128;

  const f32x4 fz = {0.f, 0.f, 0.f, 0.f};
  f32x4 acc[4][4];
#pragma unroll
  for (int i = 0; i < 4; i++)
#pragma unroll
    for (int j = 0; j < 4; j++) acc[i][j] = fz;

  const int r0 = tid >> 2, cg = (tid & 3) * 8;
  const int r1 = r0 + 64;

  Stg<u16t> sa0, sa1; Stg<float> sb0, sb1;
  sa0.ld(A  + (long)(m0 + r0) * K + cg);
  sa1.ld(A  + (long)(m0 + r1) * K + cg);
  sb0.ld(Bm + (long)(n0 + r0) * K + cg);
  sb1.ld(Bm + (long)(n0 + r1) * K + cg);

  for (int k0 = 0; k0 < K; k0 += 32) {
    __syncthreads();
    *(bf16x8*)&At[r0 * LAB + cg] = sa0.get();
    *(bf16x8*)&At[r1 * LAB + cg] = sa1.get();
    *(bf16x8*)&Bt[r0 * LAB + cg] = sb0.get();
    *(bf16x8*)&Bt[r1 * LAB + cg] = sb1.get();
    __syncthreads();
    if (k0 + 32 < K) {
      sa0.ld(A  + (long)(m0 + r0) * K + k0 + 32 + cg);
      sa1.ld(A  + (long)(m0 + r1) * K + k0 + 32 + cg);
      sb0.ld(Bm + (long)(n0 + r0) * K + k0 + 32 + cg);
      sb1.ld(Bm + (long)(n0 + r1) * K + k0 + 32 + cg);
    }

    bf16x8 af[4], bfv[4];
#pragma unroll
    for (int i = 0; i < 4; i++)
      af[i] = *(const bf16x8*)&At[(wm * 64 + i * 16 + l16) * LAB + quad * 8];
#pragma unroll
    for (int j = 0; j < 4; j++)
      bfv[j] = *(const bf16x8*)&Bt[(wn * 64 + j * 16 + l16) * LAB + quad * 8];
#pragma unroll
    for (int i = 0; i < 4; i++)
#pragma unroll
      for (int j = 0; j < 4; j++)
        acc[i][j] = __builtin_amdgcn_mfma_f32_16x16x32_bf16(af[i], bfv[j], acc[i][j], 0, 0, 0);
  }

#pragma unroll
  for (int i = 0; i < 4; i++) {
    const int rbase = m0 + wm * 64 + i * 16 + quad * 4;
#pragma unroll
    for (int j = 0; j < 4; j++) {
      const int col = n0 + wn * 64 + j * 16 + l16;
      const float bv = bias[col];
#pragma unroll
      for (int r = 0; r < 4; r++)
        Cv[(long)(rbase + r) * ND + col] = acc[i][j][r] + bv;
    }
  }
}

// ---------------------------------------------------------------------------
// Flash attention pass: per (b,h, 128-row q tile). 8 waves x 16 q rows
// (512-thread blocks). exp2-domain online softmax, DPP rotate-reduce,
// swizzled conflict-free LDS, software-pipelined K/V staging, pf hoisted
// out of the PV d-loop (d-invariant).
// Tripwire: WRITE_SIZE must stay ~17408 KB; any jump = spills -> revert.
// ---------------------------------------------------------------------------
__global__ __launch_bounds__(512, 4)
void flash_ctx(const u16t* __restrict__ Qw, const u16t* __restrict__ Kw,
               const u16t* __restrict__ VTw, const int* __restrict__ mask,
               u16t* __restrict__ ctx, float* __restrict__ mo, float* __restrict__ lo)
{
  __shared__ __attribute__((aligned(16))) u16t Kt[64 * 64];
  __shared__ __attribute__((aligned(16))) u16t Vt[64 * 64];
  __shared__ __attribute__((aligned(16))) u16t Pt[8 * 16 * 64];
  __shared__ float biasl[NS];

  const int tid  = threadIdx.x;
  const int w    = tid >> 6;
  const int lane = tid & 63;
  const int quad = lane >> 4;
  const int l16  = lane & 15;
  const int bh   = blockIdx.y;        // b*16 + h
  const int b    = bh >> 4;
  const int h    = bh & 15;
  const int qw   = blockIdx.x * 128 + w * 16;
  const int pbase = w * 1024;         // per-wave 16x64 P tile

  for (int i = tid; i < NS; i += 512)
    biasl[i] = mask[b * NS + i] ? 0.f : NEGINF;

  // preload this wave's Q fragments (16 rows x 64 d) into registers
  bf16x8 qf[2];
#pragma unroll
  for (int kk = 0; kk < 2; kk++)
    qf[kk] = *(const bf16x8*)(Qw + ((long)bh * NS + qw + l16) * NDK + kk * 32 + quad * 8);

  const f32x4 fz = {0.f, 0.f, 0.f, 0.f};
  const f32x4 fm = {NEGINF, NEGINF, NEGINF, NEGINF};
  f32x4 cacc[4];
#pragma unroll
  for (int d = 0; d < 4; d++) cacc[d] = fz;
  f32x4 mrun = fm;
  f32x4 lrun = fz;

  // staging chunk map: chunk c (0..511) -> row c>>3 (0..63), colgrp (c&7)*8
  const int kr0 = tid >> 3, kc0 = (tid & 7) * 8;
  const long kbase = (long)bh * NS;
  const long vbase = (long)bh * NDK;

  bf16x8 kv = *(const bf16x8*)(Kw  + (kbase + kr0) * NDK + kc0);
  bf16x8 vv = *(const bf16x8*)(VTw + (vbase + kr0) * NS + kc0);

  for (int kb = 0; kb < NS; kb += 64) {
    __syncthreads();
    *(bf16x8*)&Kt[swz(kr0, kc0)] = kv;
    *(bf16x8*)&Vt[swz(kr0, kc0)] = vv;
    __syncthreads();
    if (kb + 64 < NS) {   // prefetch next tile; latency hides under compute
      kv = *(const bf16x8*)(Kw  + (kbase + kb + 64 + kr0) * NDK + kc0);
      vv = *(const bf16x8*)(VTw + (vbase + kr0) * NS + kb + 64 + kc0);
    }

    // S = Q K^T (rows: q, cols: key) for this wave's 16 rows
    f32x4 s[4];
#pragma unroll
    for (int c = 0; c < 4; c++) {
      f32x4 a = fz;
#pragma unroll
      for (int kk = 0; kk < 2; kk++) {
        bf16x8 kf = *(const bf16x8*)&Kt[swz(c * 16 + l16, kk * 32 + quad * 8)];
        a = __builtin_amdgcn_mfma_f32_16x16x32_bf16(qf[kk], kf, a, 0, 0, 0);
      }
      s[c] = a;
    }

#pragma unroll
    for (int c = 0; c < 4; c++) {
      const float bias_c = biasl[kb + c * 16 + l16];
#pragma unroll
      for (int r = 0; r < 4; r++)
        s[c][r] = s[c][r] * SCALE2 + bias_c;
    }

    // row max across 4 col-frags then DPP rotate-reduce over the 16 lanes
    f32x4 mx = s[0];
#pragma unroll
    for (int c = 1; c < 4; c++)
#pragma unroll
      for (int r = 0; r < 4; r++) mx[r] = fmaxf(mx[r], s[c][r]);
#pragma unroll
    for (int r = 0; r < 4; r++) {
      float x = mx[r];
      x = fmaxf(x, ROR16(x, 1));
      x = fmaxf(x, ROR16(x, 2));
      x = fmaxf(x, ROR16(x, 4));
      x = fmaxf(x, ROR16(x, 8));
      mx[r] = x;
    }

    f32x4 alpha;
#pragma unroll
    for (int r = 0; r < 4; r++) {
      float mnew = fmaxf(mrun[r], mx[r]);
      alpha[r] = fexp2(mrun[r] - mnew);
      mrun[r] = mnew;
    }
#pragma unroll
    for (int c = 0; c < 4; c++)
#pragma unroll
      for (int r = 0; r < 4; r++) s[c][r] = fexp2(s[c][r] - mrun[r]);

    f32x4 sm = fz;
#pragma unroll
    for (int c = 0; c < 4; c++)
#pragma unroll
      for (int r = 0; r < 4; r++) sm[r] += s[c][r];
#pragma unroll
    for (int r = 0; r < 4; r++) {
      float x = sm[r];
      x += ROR16(x, 1);
      x += ROR16(x, 2);
      x += ROR16(x, 4);
      x += ROR16(x, 8);
      sm[r] = x;
    }
#pragma unroll
    for (int r = 0; r < 4; r++) lrun[r] = lrun[r] * alpha[r] + sm[r];
#pragma unroll
    for (int d = 0; d < 4; d++)
#pragma unroll
      for (int r = 0; r < 4; r++) cacc[d][r] *= alpha[r];

    // P -> LDS (A-operand layout: [q][key] row-major, swizzled)
#pragma unroll
    for (int c = 0; c < 4; c++)
#pragma unroll
      for (int r = 0; r < 4; r++)
        Pt[pbase + swz(quad * 4 + r, c * 16 + l16)] = f2bf(s[c][r]);

    // context += P * V  (per-wave Pt; same-wave DS ops are in order)
    bf16x8 pf[2];
#pragma unroll
    for (int kk = 0; kk < 2; kk++)
      pf[kk] = *(const bf16x8*)&Pt[pbase + swz(l16, kk * 32 + quad * 8)];
#pragma unroll
    for (int d = 0; d < 4; d++)
#pragma unroll
      for (int kk = 0; kk < 2; kk++) {
        bf16x8 vf = *(const bf16x8*)&Vt[swz(d * 16 + l16, kk * 32 + quad * 8)];
        cacc[d] = __builtin_amdgcn_mfma_f32_16x16x32_bf16(pf[kk], vf, cacc[d], 0, 0, 0);
      }
  }

  // epilogue: normalize, write context and (m,l)
  {
    f32x4 rinv;
#pragma unroll
    for (int r = 0; r < 4; r++) rinv[r] = 1.f / lrun[r];
#pragma unroll
    for (int d = 0; d < 4; d++)
#pragma unroll
      for (int r = 0; r < 4; r++) {
        int qg = qw + quad * 4 + r;
        int e  = h * NDK + d * 16 + l16;
        ctx[((long)(b * NS + qg)) * ND + e] = f2bf(cacc[d][r] * rinv[r]);
      }
    if (l16 == 0) {
#pragma unroll
      for (int r = 0; r < 4; r++) {
        int qg = qw + quad * 4 + r;
        mo[(long)bh * NS + qg] = mrun[r];
        lo[(long)bh * NS + qg] = lrun[r];
      }
    }
  }
}

// ---------------------------------------------------------------------------
// probs_mean: per (b, 128x128 score tile), loop all 16 heads recomputing
// S = Q K^T, p = exp2(s*SCALE2 + maskbias - m)/l, accumulate mean, fp32 out.
// Swizzled [128][64] tiles; per-head m/l staged into a 1 KB buffer inside the
// existing barrier window (was 16 KB for all heads) -> LDS ~33.5 KB -> 4
// blocks/CU resident. Software-pipelined head staging.
// ---------------------------------------------------------------------------
__global__ __launch_bounds__(256, 3)
void probs_mean(const u16t* __restrict__ Qw, const u16t* __restrict__ Kw,
                const int* __restrict__ mask, const float* __restrict__ mo,
                const float* __restrict__ lo, float* __restrict__ outp)
{
  __shared__ __attribute__((aligned(16))) u16t Qt[128 * 64];
  __shared__ __attribute__((aligned(16))) u16t Kt2[128 * 64];
  __shared__ float mlc[128];
  __shared__ float lic[128];
  __shared__ float biasl[128];

  const int tid  = threadIdx.x;
  const int w    = tid >> 6;
  const int lane = tid & 63;
  const int quad = lane >> 4;
  const int l16  = lane & 15;
  const int wm   = w >> 1, wn = w & 1;
  const int b  = blockIdx.z;
  const int q0 = blockIdx.y * 128;
  const int k0 = blockIdx.x * 128;

  for (int i = tid; i < 128; i += 256)
    biasl[i] = mask[b * NS + k0 + i] ? 0.f : NEGINF;

  const f32x4 fz = {0.f, 0.f, 0.f, 0.f};
  f32x4 acc[4][4];
#pragma unroll
  for (int i = 0; i < 4; i++)
#pragma unroll
    for (int j = 0; j < 4; j++) acc[i][j] = fz;

  // prefetch head 0: Q/K tiles + this thread's m-or-l value
  bf16x8 qv[4], kv[4];
#pragma unroll
  for (int rr = 0; rr < 4; rr++) {
    int idx = rr * 256 + tid;
    int row = idx >> 3, off = (idx & 7) * 8;
    qv[rr] = *(const bf16x8*)(Qw + ((long)(b * NH) * NS + q0 + row) * NDK + off);
    kv[rr] = *(const bf16x8*)(Kw + ((long)(b * NH) * NS + k0 + row) * NDK + off);
  }
  float mlpref = (tid < 128) ? mo[((long)(b * NH)) * NS + q0 + tid]
                             : lo[((long)(b * NH)) * NS + q0 + (tid & 127)];

  for (int hh = 0; hh < NH; hh++) {
    __syncthreads();
#pragma unroll
    for (int rr = 0; rr < 4; rr++) {
      int idx = rr * 256 + tid;
      int row = idx >> 3, off = (idx & 7) * 8;
      *(bf16x8*)&Qt[swz(row, off)]  = qv[rr];
      *(bf16x8*)&Kt2[swz(row, off)] = kv[rr];
    }
    if (tid < 128) mlc[tid] = mlpref;
    else           lic[tid & 127] = 1.f / mlpref;
    __syncthreads();
    if (hh + 1 < NH) {
#pragma unroll
      for (int rr = 0; rr < 4; rr++) {
        int idx = rr * 256 + tid;
        int row = idx >> 3, off = (idx & 7) * 8;
        qv[rr] = *(const bf16x8*)(Qw + ((long)(b * NH + hh + 1) * NS + q0 + row) * NDK + off);
        kv[rr] = *(const bf16x8*)(Kw + ((long)(b * NH + hh + 1) * NS + k0 + row) * NDK + off);
      }
      mlpref = (tid < 128) ? mo[((long)(b * NH + hh + 1)) * NS + q0 + tid]
                           : lo[((long)(b * NH + hh + 1)) * NS + q0 + (tid & 127)];
    }

    bf16x8 af[4][2], bfv[4][2];
#pragma unroll
    for (int i = 0; i < 4; i++)
#pragma unroll
      for (int kk = 0; kk < 2; kk++) {
        af[i][kk]  = *(const bf16x8*)&Qt[swz(wm * 64 + i * 16 + l16, kk * 32 + quad * 8)];
        bfv[i][kk] = *(const bf16x8*)&Kt2[swz(wn * 64 + i * 16 + l16, kk * 32 + quad * 8)];
      }
#pragma unroll
    for (int i = 0; i < 4; i++)
#pragma unroll
      for (int j = 0; j < 4; j++) {
        f32x4 s = fz;
#pragma unroll
        for (int kk = 0; kk < 2; kk++)
          s = __builtin_amdgcn_mfma_f32_16x16x32_bf16(af[i][kk], bfv[j][kk], s, 0, 0, 0);
        const float bias_c = biasl[wn * 64 + j * 16 + l16];
#pragma unroll
        for (int r = 0; r < 4; r++) {
          int rowb = wm * 64 + i * 16 + quad * 4 + r;
          float p = fexp2(s[r] * SCALE2 + bias_c - mlc[rowb]) * lic[rowb];
          acc[i][j][r] += p;
        }
      }
  }

#pragma unroll
  for (int i = 0; i < 4; i++)
#pragma unroll
    for (int j = 0; j < 4; j++)
#pragma unroll
      for (int r = 0; r < 4; r++) {
        int row = q0 + wm * 64 + i * 16 + quad * 4 + r;
        int col = k0 + wn * 64 + j * 16 + l16;
        outp[((long)(b * NS + row)) * NS + col] = acc[i][j][r] * (1.f / 16.f);
      }
}

// ---------------------------------------------------------------------------
extern "C" void kernel_launch(void* const* d_in, const int* in_sizes, int n_in,
                              void* d_out, int out_size, void* d_ws, size_t ws_size,
                              hipStream_t stream)
{
  (void)in_sizes; (void)n_in; (void)out_size; (void)ws_size;
  const float* query = (const float*)d_in[0];
  const float* keyt  = (const float*)d_in[1];
  const float* value = (const float*)d_in[2];
  const int*   mask  = (const int*)d_in[3];
  const float* Wq = (const float*)d_in[4];
  const float* Wk = (const float*)d_in[5];
  const float* Wv = (const float*)d_in[6];
  const float* Wo = (const float*)d_in[7];
  const float* bo = (const float*)d_in[8];

  float* out  = (float*)d_out;                     // [B,S,D] fp32
  float* outp = out + (long)NB * NS * ND;          // [B,S,S] fp32

  u16t* q_ws  = (u16t*)d_ws;                       // [B,H,S,dk] bf16
  u16t* k_ws  = q_ws + (long)NB * NH * NS * NDK;   // [B,H,S,dk] bf16
  u16t* vt_ws = k_ws + (long)NB * NH * NS * NDK;   // [B,H,dk,S] bf16
  float* m_ws = (float*)(vt_ws + (long)NB * NH * NS * NDK);
  float* l_ws = m_ws + (long)NB * NH * NS;
  // ctx scratch (bf16) lives in the outp region of d_out; it is fully
  // consumed by the output GEMM before probs_mean overwrites the region.
  u16t* ctx_ws = (u16t*)outp;

  dim3 blk(256);
  qkv_proj<<<dim3(64, 8, 3), blk, 0, stream>>>(query, keyt, value, Wq, Wk, Wv,
                                               q_ws, k_ws, vt_ws);
  flash_ctx<<<dim3(NS / 128, NB * NH), dim3(512), 0, stream>>>(q_ws, k_ws, vt_ws, mask,
                                                               ctx_ws, m_ws, l_ws);
  gemm_out<<<dim3(64, 8), blk, 0, stream>>>(ctx_ws, Wo, out, bo);
  probs_mean<<<dim3(NS / 128, NS / 128, NB), blk, 0, stream>>>(q_ws, k_ws, mask,
                                                               m_ws, l_ws, outp);
}

// Round 8
// 533.532 us; speedup vs baseline: 1.0177x; 1.0177x over previous
//
#include <hip/hip_runtime.h>

typedef unsigned short u16t;
typedef __bf16 bf16x8 __attribute__((ext_vector_type(8)));
typedef float f32x4 __attribute__((ext_vector_type(4)));

#define NB 4
#define NS 2048
#define ND 1024
#define NH 16
#define NDK 64
#define NEGINF -1.0e9f
// softmax runs in exp2 domain: SCALE2 = 0.125 * log2(e)
#define SCALE2 0.18033688011112042f

// padded LDS row stride for gemm (32-wide tiles): 40 elem = 80B, 5 granules,
// coprime with 8 -> conflict-free frag reads.
#define LAB 40

__device__ __forceinline__ float fexp2(float x) { return __builtin_amdgcn_exp2f(x); }

// native bf16 convert (RNE via v_cvt_pk_bf16_f32; 1 inst vs 3 bit-ops)
__device__ __forceinline__ u16t f2bf(float f) {
  return __builtin_bit_cast(u16t, (__bf16)f);
}

// DPP rotate within 16-lane rows (softmax reduce: VALU pipe, ~3 cyc/step vs
// ~35 cyc ds_bpermute for shfl). Correctness verified R2/R5/R6.
#define ROR16(x, n) __builtin_bit_cast(float, __builtin_amdgcn_update_dpp(     \
    __builtin_bit_cast(int, (x)), __builtin_bit_cast(int, (x)),                \
    0x120 + (n), 0xF, 0xF, false))

// XOR-swizzle index for [*][64] u16 tiles (128B row stride): rotates 16B
// granules within each 8-row stripe. Verified 0 conflicts since R2.
__device__ __forceinline__ int swz(int row, int col) {
  return row * 64 + (col ^ ((row & 7) << 3));
}
// same for [*][128] u16 tiles (256B row stride; granule period still 8/row-set)
__device__ __forceinline__ int swzV(int row, int col) {
  return row * 128 + (col ^ ((row & 7) << 3));
}

// register staging helpers (raw loads now, convert at LDS-store time)
template<typename TA> struct Stg;
template<> struct Stg<float> {
  f32x4 lo, hi;
  __device__ __forceinline__ void ld(const float* p) {
    lo = *(const f32x4*)p; hi = *(const f32x4*)(p + 4);
  }
  __device__ __forceinline__ bf16x8 get() const {
    bf16x8 r;
    r[0] = (__bf16)lo[0]; r[1] = (__bf16)lo[1]; r[2] = (__bf16)lo[2]; r[3] = (__bf16)lo[3];
    r[4] = (__bf16)hi[0]; r[5] = (__bf16)hi[1]; r[6] = (__bf16)hi[2]; r[7] = (__bf16)hi[3];
    return r;
  }
};
template<> struct Stg<u16t> {
  bf16x8 v;
  __device__ __forceinline__ void ld(const u16t* p) { v = *(const bf16x8*)p; }
  __device__ __forceinline__ bf16x8 get() const { return v; }
};

// ---------------------------------------------------------------------------
// NT GEMM: C[M,N] = A[M,K] * B[N,K]^T ; M=8192, N=K=1024, bf16 MFMA, fp32 acc.
// MODE 0: C fp32 row-major [M,N] + bias[col]   (output projection -> d_out)
// MODE 1: C bf16 scatter to [B,H,S,dk]         (Q/K projections -> ws)
// MODE 2: C bf16 scatter to [B,H,dk,S]         (V projection, transposed -> ws)
// Software-pipelined: next K-step's global loads issue before the MFMA block.
// ---------------------------------------------------------------------------
template<typename TA, int MODE>
__global__ __launch_bounds__(256, 2)
void gemm_nt(const TA* __restrict__ A, const float* __restrict__ Bm,
             void* __restrict__ Cv, const float* __restrict__ bias)
{
  const int K = 1024;
  __shared__ __attribute__((aligned(16))) u16t At[128 * LAB];
  __shared__ __attribute__((aligned(16))) u16t Bt[128 * LAB];

  const int tid  = threadIdx.x;
  const int w    = tid >> 6;
  const int lane = tid & 63;
  const int quad = lane >> 4;
  const int l16  = lane & 15;
  const int wm   = w >> 1, wn = w & 1;
  const int m0   = blockIdx.x * 128;
  const int n0   = blockIdx.y * 128;

  const f32x4 fz = {0.f, 0.f, 0.f, 0.f};
  f32x4 acc[4][4];
#pragma unroll
  for (int i = 0; i < 4; i++)
#pragma unroll
    for (int j = 0; j < 4; j++) acc[i][j] = fz;

  // staging chunk map: chunk c (0..511) -> row c>>2 (0..127), colgrp (c&3)*8
  const int r0 = tid >> 2, cg = (tid & 3) * 8;
  const int r1 = r0 + 64;

  Stg<TA> sa0, sa1; Stg<float> sb0, sb1;
  sa0.ld(A  + (long)(m0 + r0) * K + cg);
  sa1.ld(A  + (long)(m0 + r1) * K + cg);
  sb0.ld(Bm + (long)(n0 + r0) * K + cg);
  sb1.ld(Bm + (long)(n0 + r1) * K + cg);

  for (int k0 = 0; k0 < K; k0 += 32) {
    __syncthreads();
    *(bf16x8*)&At[r0 * LAB + cg] = sa0.get();
    *(bf16x8*)&At[r1 * LAB + cg] = sa1.get();
    *(bf16x8*)&Bt[r0 * LAB + cg] = sb0.get();
    *(bf16x8*)&Bt[r1 * LAB + cg] = sb1.get();
    __syncthreads();
    if (k0 + 32 < K) {
      sa0.ld(A  + (long)(m0 + r0) * K + k0 + 32 + cg);
      sa1.ld(A  + (long)(m0 + r1) * K + k0 + 32 + cg);
      sb0.ld(Bm + (long)(n0 + r0) * K + k0 + 32 + cg);
      sb1.ld(Bm + (long)(n0 + r1) * K + k0 + 32 + cg);
    }

    bf16x8 af[4], bfv[4];
#pragma unroll
    for (int i = 0; i < 4; i++)
      af[i] = *(const bf16x8*)&At[(wm * 64 + i * 16 + l16) * LAB + quad * 8];
#pragma unroll
    for (int j = 0; j < 4; j++)
      bfv[j] = *(const bf16x8*)&Bt[(wn * 64 + j * 16 + l16) * LAB + quad * 8];
#pragma unroll
    for (int i = 0; i < 4; i++)
#pragma unroll
      for (int j = 0; j < 4; j++)
        acc[i][j] = __builtin_amdgcn_mfma_f32_16x16x32_bf16(af[i], bfv[j], acc[i][j], 0, 0, 0);
  }

#pragma unroll
  for (int i = 0; i < 4; i++) {
    const int rbase = m0 + wm * 64 + i * 16 + quad * 4;
#pragma unroll
    for (int j = 0; j < 4; j++) {
      const int col = n0 + wn * 64 + j * 16 + l16;
      float bv = 0.f;
      if (MODE == 0) bv = bias[col];
#pragma unroll
      for (int r = 0; r < 4; r++) {
        const int row = rbase + r;
        float v = acc[i][j][r];
        if (MODE == 0) {
          ((float*)Cv)[(long)row * ND + col] = v + bv;
        } else if (MODE == 1) {
          int b = row >> 11, s = row & 2047, h = col >> 6, d = col & 63;
          ((u16t*)Cv)[(((long)(b * NH + h)) * NS + s) * NDK + d] = f2bf(v);
        } else {
          int b = row >> 11, s = row & 2047, h = col >> 6, d = col & 63;
          ((u16t*)Cv)[(((long)(b * NH + h)) * NDK + d) * NS + s] = f2bf(v);
        }
      }
    }
  }
}

// ---------------------------------------------------------------------------
// Flash attention pass: per (b,h, 128-row q tile). 8 waves x 16 q rows
// (512-thread blocks). KVBLK=128: one softmax reduce pair + one rescale +
// one barrier pair per 128 keys (was per 64) -- halves the serial VALU
// overhead on a 70%-VALU-busy kernel. PV runs as two 64-key halves through
// the per-wave Pt region (same-wave DS ordering). exp2-domain online
// softmax, DPP rotate-reduce, swizzled conflict-free LDS, software-pipelined
// K/V staging. LDS 56 KB -> 2 blocks/CU (16 waves).
// Tripwire: WRITE_SIZE must stay ~17408 KB; any jump = spills -> revert.
// ---------------------------------------------------------------------------
__global__ __launch_bounds__(512, 4)
void flash_ctx(const u16t* __restrict__ Qw, const u16t* __restrict__ Kw,
               const u16t* __restrict__ VTw, const int* __restrict__ mask,
               u16t* __restrict__ ctx, float* __restrict__ mo, float* __restrict__ lo)
{
  __shared__ __attribute__((aligned(16))) u16t Kt[128 * 64];
  __shared__ __attribute__((aligned(16))) u16t Vt[64 * 128];
  __shared__ __attribute__((aligned(16))) u16t Pt[8 * 16 * 64];
  __shared__ float biasl[NS];

  const int tid  = threadIdx.x;
  const int w    = tid >> 6;
  const int lane = tid & 63;
  const int quad = lane >> 4;
  const int l16  = lane & 15;
  const int bh   = blockIdx.y;        // b*16 + h
  const int b    = bh >> 4;
  const int h    = bh & 15;
  const int qw   = blockIdx.x * 128 + w * 16;
  const int pbase = w * 1024;         // per-wave 16x64 P tile

  for (int i = tid; i < NS; i += 512)
    biasl[i] = mask[b * NS + i] ? 0.f : NEGINF;

  // preload this wave's Q fragments (16 rows x 64 d) into registers
  bf16x8 qf[2];
#pragma unroll
  for (int kk = 0; kk < 2; kk++)
    qf[kk] = *(const bf16x8*)(Qw + ((long)bh * NS + qw + l16) * NDK + kk * 32 + quad * 8);

  const f32x4 fz = {0.f, 0.f, 0.f, 0.f};
  const f32x4 fm = {NEGINF, NEGINF, NEGINF, NEGINF};
  f32x4 cacc[4];
#pragma unroll
  for (int d = 0; d < 4; d++) cacc[d] = fz;
  f32x4 mrun = fm;
  f32x4 lrun = fz;

  // staging maps (128x64 K tile, 64x128 V tile; 2 contiguous 16B loads each)
  const int kr = tid >> 2, kc = (tid & 3) * 16;   // K: rows 0..127
  const int vr = tid >> 3, vc = (tid & 7) * 16;   // V: rows 0..63
  const long kbase = (long)bh * NS;
  const long vbase = (long)bh * NDK;

  bf16x8 kva = *(const bf16x8*)(Kw  + (kbase + kr) * NDK + kc);
  bf16x8 kvb = *(const bf16x8*)(Kw  + (kbase + kr) * NDK + kc + 8);
  bf16x8 vva = *(const bf16x8*)(VTw + (vbase + vr) * NS + vc);
  bf16x8 vvb = *(const bf16x8*)(VTw + (vbase + vr) * NS + vc + 8);

  for (int kb = 0; kb < NS; kb += 128) {
    __syncthreads();
    *(bf16x8*)&Kt[swz(kr, kc)]      = kva;
    *(bf16x8*)&Kt[swz(kr, kc + 8)]  = kvb;
    *(bf16x8*)&Vt[swzV(vr, vc)]     = vva;
    *(bf16x8*)&Vt[swzV(vr, vc + 8)] = vvb;
    __syncthreads();
    if (kb + 128 < NS) {   // prefetch next tile; latency hides under compute
      kva = *(const bf16x8*)(Kw  + (kbase + kb + 128 + kr) * NDK + kc);
      kvb = *(const bf16x8*)(Kw  + (kbase + kb + 128 + kr) * NDK + kc + 8);
      vva = *(const bf16x8*)(VTw + (vbase + vr) * NS + kb + 128 + vc);
      vvb = *(const bf16x8*)(VTw + (vbase + vr) * NS + kb + 128 + vc + 8);
    }

    // S = Q K^T (rows: q, cols: 128 keys) for this wave's 16 rows
    f32x4 s[8];
#pragma unroll
    for (int c = 0; c < 8; c++) {
      f32x4 a = fz;
#pragma unroll
      for (int kk = 0; kk < 2; kk++) {
        bf16x8 kf = *(const bf16x8*)&Kt[swz(c * 16 + l16, kk * 32 + quad * 8)];
        a = __builtin_amdgcn_mfma_f32_16x16x32_bf16(qf[kk], kf, a, 0, 0, 0);
      }
      s[c] = a;
    }

#pragma unroll
    for (int c = 0; c < 8; c++) {
      const float bias_c = biasl[kb + c * 16 + l16];
#pragma unroll
      for (int r = 0; r < 4; r++)
        s[c][r] = s[c][r] * SCALE2 + bias_c;
    }

    // row max across 8 col-frags then DPP rotate-reduce over the 16 lanes
    f32x4 mx = s[0];
#pragma unroll
    for (int c = 1; c < 8; c++)
#pragma unroll
      for (int r = 0; r < 4; r++) mx[r] = fmaxf(mx[r], s[c][r]);
#pragma unroll
    for (int r = 0; r < 4; r++) {
      float x = mx[r];
      x = fmaxf(x, ROR16(x, 1));
      x = fmaxf(x, ROR16(x, 2));
      x = fmaxf(x, ROR16(x, 4));
      x = fmaxf(x, ROR16(x, 8));
      mx[r] = x;
    }

    f32x4 alpha;
#pragma unroll
    for (int r = 0; r < 4; r++) {
      float mnew = fmaxf(mrun[r], mx[r]);
      alpha[r] = fexp2(mrun[r] - mnew);
      mrun[r] = mnew;
    }
#pragma unroll
    for (int c = 0; c < 8; c++)
#pragma unroll
      for (int r = 0; r < 4; r++) s[c][r] = fexp2(s[c][r] - mrun[r]);

    f32x4 sm = fz;
#pragma unroll
    for (int c = 0; c < 8; c++)
#pragma unroll
      for (int r = 0; r < 4; r++) sm[r] += s[c][r];
#pragma unroll
    for (int r = 0; r < 4; r++) {
      float x = sm[r];
      x += ROR16(x, 1);
      x += ROR16(x, 2);
      x += ROR16(x, 4);
      x += ROR16(x, 8);
      sm[r] = x;
    }
#pragma unroll
    for (int r = 0; r < 4; r++) lrun[r] = lrun[r] * alpha[r] + sm[r];
#pragma unroll
    for (int d = 0; d < 4; d++)
#pragma unroll
      for (int r = 0; r < 4; r++) cacc[d][r] *= alpha[r];

    // PV in two 64-key halves through the per-wave Pt region (same-wave DS
    // ops execute in order, so half 1's writes can't pass half 0's reads).
#pragma unroll
    for (int hk = 0; hk < 2; hk++) {
#pragma unroll
      for (int c2 = 0; c2 < 4; c2++)
#pragma unroll
        for (int r = 0; r < 4; r++)
          Pt[pbase + swz(quad * 4 + r, c2 * 16 + l16)] = f2bf(s[hk * 4 + c2][r]);

      bf16x8 pf[2];
#pragma unroll
      for (int kk = 0; kk < 2; kk++)
        pf[kk] = *(const bf16x8*)&Pt[pbase + swz(l16, kk * 32 + quad * 8)];
#pragma unroll
      for (int d = 0; d < 4; d++)
#pragma unroll
        for (int kk = 0; kk < 2; kk++) {
          bf16x8 vf = *(const bf16x8*)&Vt[swzV(d * 16 + l16, hk * 64 + kk * 32 + quad * 8)];
          cacc[d] = __builtin_amdgcn_mfma_f32_16x16x32_bf16(pf[kk], vf, cacc[d], 0, 0, 0);
        }
    }
  }

  // epilogue: normalize, write context and (m,l)
  {
    f32x4 rinv;
#pragma unroll
    for (int r = 0; r < 4; r++) rinv[r] = 1.f / lrun[r];
#pragma unroll
    for (int d = 0; d < 4; d++)
#pragma unroll
      for (int r = 0; r < 4; r++) {
        int qg = qw + quad * 4 + r;
        int e  = h * NDK + d * 16 + l16;
        ctx[((long)(b * NS + qg)) * ND + e] = f2bf(cacc[d][r] * rinv[r]);
      }
    if (l16 == 0) {
#pragma unroll
      for (int r = 0; r < 4; r++) {
        int qg = qw + quad * 4 + r;
        mo[(long)bh * NS + qg] = mrun[r];
        lo[(long)bh * NS + qg] = lrun[r];
      }
    }
  }
}

// ---------------------------------------------------------------------------
// probs_mean: per (b, 128x128 score tile), loop all 16 heads recomputing
// S = Q K^T, p = exp2(s*SCALE2 + maskbias - m)/l, accumulate mean, fp32 out.
// Swizzled [128][64] tiles; full ml/li preload (R6 form — the R7 per-head
// staging variant regressed). Software-pipelined head staging.
// ---------------------------------------------------------------------------
__global__ __launch_bounds__(256, 3)
void probs_mean(const u16t* __restrict__ Qw, const u16t* __restrict__ Kw,
                const int* __restrict__ mask, const float* __restrict__ mo,
                const float* __restrict__ lo, float* __restrict__ outp)
{
  __shared__ __attribute__((aligned(16))) u16t Qt[128 * 64];
  __shared__ __attribute__((aligned(16))) u16t Kt2[128 * 64];
  __shared__ float ml[NH * 128];
  __shared__ float li[NH * 128];
  __shared__ float biasl[128];

  const int tid  = threadIdx.x;
  const int w    = tid >> 6;
  const int lane = tid & 63;
  const int quad = lane >> 4;
  const int l16  = lane & 15;
  const int wm   = w >> 1, wn = w & 1;
  const int b  = blockIdx.z;
  const int q0 = blockIdx.y * 128;
  const int k0 = blockIdx.x * 128;

  for (int i = tid; i < NH * 128; i += 256) {
    int hh = i >> 7, r = i & 127;
    ml[i] = mo[((long)(b * NH + hh)) * NS + q0 + r];
    li[i] = 1.f / lo[((long)(b * NH + hh)) * NS + q0 + r];
  }
  for (int i = tid; i < 128; i += 256)
    biasl[i] = mask[b * NS + k0 + i] ? 0.f : NEGINF;

  const f32x4 fz = {0.f, 0.f, 0.f, 0.f};
  f32x4 acc[4][4];
#pragma unroll
  for (int i = 0; i < 4; i++)
#pragma unroll
    for (int j = 0; j < 4; j++) acc[i][j] = fz;

  bf16x8 qv[4], kv[4];
#pragma unroll
  for (int rr = 0; rr < 4; rr++) {
    int idx = rr * 256 + tid;
    int row = idx >> 3, off = (idx & 7) * 8;
    qv[rr] = *(const bf16x8*)(Qw + ((long)(b * NH) * NS + q0 + row) * NDK + off);
    kv[rr] = *(const bf16x8*)(Kw + ((long)(b * NH) * NS + k0 + row) * NDK + off);
  }

  for (int hh = 0; hh < NH; hh++) {
    __syncthreads();
#pragma unroll
    for (int rr = 0; rr < 4; rr++) {
      int idx = rr * 256 + tid;
      int row = idx >> 3, off = (idx & 7) * 8;
      *(bf16x8*)&Qt[swz(row, off)]  = qv[rr];
      *(bf16x8*)&Kt2[swz(row, off)] = kv[rr];
    }
    __syncthreads();
    if (hh + 1 < NH) {
#pragma unroll
      for (int rr = 0; rr < 4; rr++) {
        int idx = rr * 256 + tid;
        int row = idx >> 3, off = (idx & 7) * 8;
        qv[rr] = *(const bf16x8*)(Qw + ((long)(b * NH + hh + 1) * NS + q0 + row) * NDK + off);
        kv[rr] = *(const bf16x8*)(Kw + ((long)(b * NH + hh + 1) * NS + k0 + row) * NDK + off);
      }
    }

    bf16x8 af[4][2], bfv[4][2];
#pragma unroll
    for (int i = 0; i < 4; i++)
#pragma unroll
      for (int kk = 0; kk < 2; kk++) {
        af[i][kk]  = *(const bf16x8*)&Qt[swz(wm * 64 + i * 16 + l16, kk * 32 + quad * 8)];
        bfv[i][kk] = *(const bf16x8*)&Kt2[swz(wn * 64 + i * 16 + l16, kk * 32 + quad * 8)];
      }
#pragma unroll
    for (int i = 0; i < 4; i++)
#pragma unroll
      for (int j = 0; j < 4; j++) {
        f32x4 s = fz;
#pragma unroll
        for (int kk = 0; kk < 2; kk++)
          s = __builtin_amdgcn_mfma_f32_16x16x32_bf16(af[i][kk], bfv[j][kk], s, 0, 0, 0);
        const float bias_c = biasl[wn * 64 + j * 16 + l16];
#pragma unroll
        for (int r = 0; r < 4; r++) {
          int rowb = wm * 64 + i * 16 + quad * 4 + r;
          float p = fexp2(s[r] * SCALE2 + bias_c - ml[hh * 128 + rowb]) * li[hh * 128 + rowb];
          acc[i][j][r] += p;
        }
      }
  }

#pragma unroll
  for (int i = 0; i < 4; i++)
#pragma unroll
    for (int j = 0; j < 4; j++)
#pragma unroll
      for (int r = 0; r < 4; r++) {
        int row = q0 + wm * 64 + i * 16 + quad * 4 + r;
        int col = k0 + wn * 64 + j * 16 + l16;
        outp[((long)(b * NS + row)) * NS + col] = acc[i][j][r] * (1.f / 16.f);
      }
}

// ---------------------------------------------------------------------------
extern "C" void kernel_launch(void* const* d_in, const int* in_sizes, int n_in,
                              void* d_out, int out_size, void* d_ws, size_t ws_size,
                              hipStream_t stream)
{
  (void)in_sizes; (void)n_in; (void)out_size; (void)ws_size;
  const float* query = (const float*)d_in[0];
  const float* keyt  = (const float*)d_in[1];
  const float* value = (const float*)d_in[2];
  const int*   mask  = (const int*)d_in[3];
  const float* Wq = (const float*)d_in[4];
  const float* Wk = (const float*)d_in[5];
  const float* Wv = (const float*)d_in[6];
  const float* Wo = (const float*)d_in[7];
  const float* bo = (const float*)d_in[8];

  float* out  = (float*)d_out;                     // [B,S,D] fp32
  float* outp = out + (long)NB * NS * ND;          // [B,S,S] fp32

  u16t* q_ws  = (u16t*)d_ws;                       // [B,H,S,dk] bf16
  u16t* k_ws  = q_ws + (long)NB * NH * NS * NDK;   // [B,H,S,dk] bf16
  u16t* vt_ws = k_ws + (long)NB * NH * NS * NDK;   // [B,H,dk,S] bf16
  float* m_ws = (float*)(vt_ws + (long)NB * NH * NS * NDK);
  float* l_ws = m_ws + (long)NB * NH * NS;
  // ctx scratch (bf16) lives in the outp region of d_out; it is fully
  // consumed by the output GEMM before probs_mean overwrites the region.
  u16t* ctx_ws = (u16t*)outp;

  dim3 blk(256);
  gemm_nt<float, 1><<<dim3(64, 8), blk, 0, stream>>>(query, Wq, q_ws, nullptr);
  gemm_nt<float, 1><<<dim3(64, 8), blk, 0, stream>>>(keyt,  Wk, k_ws, nullptr);
  gemm_nt<float, 2><<<dim3(64, 8), blk, 0, stream>>>(value, Wv, vt_ws, nullptr);
  flash_ctx<<<dim3(NS / 128, NB * NH), dim3(512), 0, stream>>>(q_ws, k_ws, vt_ws, mask,
                                                               ctx_ws, m_ws, l_ws);
  gemm_nt<u16t, 0><<<dim3(64, 8), blk, 0, stream>>>(ctx_ws, Wo, out, bo);
  probs_mean<<<dim3(NS / 128, NS / 128, NB), blk, 0, stream>>>(q_ws, k_ws, mask,
                                                               m_ws, l_ws, outp);
}

// Round 9
// 518.468 us; speedup vs baseline: 1.0473x; 1.0291x over previous
//
#include <hip/hip_runtime.h>

typedef unsigned short u16t;
typedef __bf16 bf16x8 __attribute__((ext_vector_type(8)));
typedef float f32x4 __attribute__((ext_vector_type(4)));

#define NB 4
#define NS 2048
#define ND 1024
#define NH 16
#define NDK 64
#define NEGINF -1.0e9f
// softmax runs in exp2 domain: SCALE2 = 0.125 * log2(e)
#define SCALE2 0.18033688011112042f

// padded LDS row stride for gemm (32-wide tiles): 40 elem = 80B, 5 granules,
// coprime with 8 -> conflict-free frag reads.
#define LAB 40

__device__ __forceinline__ float fexp2(float x) { return __builtin_amdgcn_exp2f(x); }

// native bf16 convert (RNE via v_cvt_pk_bf16_f32; 1 inst vs 3 bit-ops)
__device__ __forceinline__ u16t f2bf(float f) {
  return __builtin_bit_cast(u16t, (__bf16)f);
}

// DPP rotate within 16-lane rows (softmax reduce: VALU pipe, ~3 cyc/step vs
// ~35 cyc ds_bpermute for shfl). Correctness verified R2/R5/R6.
#define ROR16(x, n) __builtin_bit_cast(float, __builtin_amdgcn_update_dpp(     \
    __builtin_bit_cast(int, (x)), __builtin_bit_cast(int, (x)),                \
    0x120 + (n), 0xF, 0xF, false))

// XOR-swizzle index for [*][64] u16 tiles (128B row stride): rotates 16B
// granules within each 8-row stripe. Verified 0 conflicts since R2.
// R8 lesson: this does NOT extend to 128-wide (256B-stride) tiles — swzV
// showed 1.05e7 conflicts. Keep all flash tiles 64-wide.
__device__ __forceinline__ int swz(int row, int col) {
  return row * 64 + (col ^ ((row & 7) << 3));
}

// register staging helpers (raw loads now, convert at LDS-store time)
template<typename TA> struct Stg;
template<> struct Stg<float> {
  f32x4 lo, hi;
  __device__ __forceinline__ void ld(const float* p) {
    lo = *(const f32x4*)p; hi = *(const f32x4*)(p + 4);
  }
  __device__ __forceinline__ bf16x8 get() const {
    bf16x8 r;
    r[0] = (__bf16)lo[0]; r[1] = (__bf16)lo[1]; r[2] = (__bf16)lo[2]; r[3] = (__bf16)lo[3];
    r[4] = (__bf16)hi[0]; r[5] = (__bf16)hi[1]; r[6] = (__bf16)hi[2]; r[7] = (__bf16)hi[3];
    return r;
  }
};
template<> struct Stg<u16t> {
  bf16x8 v;
  __device__ __forceinline__ void ld(const u16t* p) { v = *(const bf16x8*)p; }
  __device__ __forceinline__ bf16x8 get() const { return v; }
};

// ---------------------------------------------------------------------------
// NT GEMM: C[M,N] = A[M,K] * B[N,K]^T ; M=8192, N=K=1024, bf16 MFMA, fp32 acc.
// MODE 0: C fp32 row-major [M,N] + bias[col]   (output projection -> d_out)
// MODE 1: C bf16 scatter to [B,H,S,dk]         (Q/K projections -> ws)
// MODE 2: C bf16 scatter to [B,H,dk,S]         (V projection, transposed -> ws)
// Software-pipelined: next K-step's global loads issue before the MFMA block.
// ---------------------------------------------------------------------------
template<typename TA, int MODE>
__global__ __launch_bounds__(256, 2)
void gemm_nt(const TA* __restrict__ A, const float* __restrict__ Bm,
             void* __restrict__ Cv, const float* __restrict__ bias)
{
  const int K = 1024;
  __shared__ __attribute__((aligned(16))) u16t At[128 * LAB];
  __shared__ __attribute__((aligned(16))) u16t Bt[128 * LAB];

  const int tid  = threadIdx.x;
  const int w    = tid >> 6;
  const int lane = tid & 63;
  const int quad = lane >> 4;
  const int l16  = lane & 15;
  const int wm   = w >> 1, wn = w & 1;
  const int m0   = blockIdx.x * 128;
  const int n0   = blockIdx.y * 128;

  const f32x4 fz = {0.f, 0.f, 0.f, 0.f};
  f32x4 acc[4][4];
#pragma unroll
  for (int i = 0; i < 4; i++)
#pragma unroll
    for (int j = 0; j < 4; j++) acc[i][j] = fz;

  // staging chunk map: chunk c (0..511) -> row c>>2 (0..127), colgrp (c&3)*8
  const int r0 = tid >> 2, cg = (tid & 3) * 8;
  const int r1 = r0 + 64;

  Stg<TA> sa0, sa1; Stg<float> sb0, sb1;
  sa0.ld(A  + (long)(m0 + r0) * K + cg);
  sa1.ld(A  + (long)(m0 + r1) * K + cg);
  sb0.ld(Bm + (long)(n0 + r0) * K + cg);
  sb1.ld(Bm + (long)(n0 + r1) * K + cg);

  for (int k0 = 0; k0 < K; k0 += 32) {
    __syncthreads();
    *(bf16x8*)&At[r0 * LAB + cg] = sa0.get();
    *(bf16x8*)&At[r1 * LAB + cg] = sa1.get();
    *(bf16x8*)&Bt[r0 * LAB + cg] = sb0.get();
    *(bf16x8*)&Bt[r1 * LAB + cg] = sb1.get();
    __syncthreads();
    if (k0 + 32 < K) {
      sa0.ld(A  + (long)(m0 + r0) * K + k0 + 32 + cg);
      sa1.ld(A  + (long)(m0 + r1) * K + k0 + 32 + cg);
      sb0.ld(Bm + (long)(n0 + r0) * K + k0 + 32 + cg);
      sb1.ld(Bm + (long)(n0 + r1) * K + k0 + 32 + cg);
    }

    bf16x8 af[4], bfv[4];
#pragma unroll
    for (int i = 0; i < 4; i++)
      af[i] = *(const bf16x8*)&At[(wm * 64 + i * 16 + l16) * LAB + quad * 8];
#pragma unroll
    for (int j = 0; j < 4; j++)
      bfv[j] = *(const bf16x8*)&Bt[(wn * 64 + j * 16 + l16) * LAB + quad * 8];
#pragma unroll
    for (int i = 0; i < 4; i++)
#pragma unroll
      for (int j = 0; j < 4; j++)
        acc[i][j] = __builtin_amdgcn_mfma_f32_16x16x32_bf16(af[i], bfv[j], acc[i][j], 0, 0, 0);
  }

#pragma unroll
  for (int i = 0; i < 4; i++) {
    const int rbase = m0 + wm * 64 + i * 16 + quad * 4;
#pragma unroll
    for (int j = 0; j < 4; j++) {
      const int col = n0 + wn * 64 + j * 16 + l16;
      float bv = 0.f;
      if (MODE == 0) bv = bias[col];
#pragma unroll
      for (int r = 0; r < 4; r++) {
        const int row = rbase + r;
        float v = acc[i][j][r];
        if (MODE == 0) {
          ((float*)Cv)[(long)row * ND + col] = v + bv;
        } else if (MODE == 1) {
          int b = row >> 11, s = row & 2047, h = col >> 6, d = col & 63;
          ((u16t*)Cv)[(((long)(b * NH + h)) * NS + s) * NDK + d] = f2bf(v);
        } else {
          int b = row >> 11, s = row & 2047, h = col >> 6, d = col & 63;
          ((u16t*)Cv)[(((long)(b * NH + h)) * NDK + d) * NS + s] = f2bf(v);
        }
      }
    }
  }
}

// ---------------------------------------------------------------------------
// Flash attention pass: per (b,h, 128-row q tile). 8 waves x 16 q rows
// (512-thread blocks). KVBLK=64 (R6 form; R8's KVBLK=128 spilled + V-tile
// conflicted). exp2-domain online softmax, DPP rotate-reduce, swizzled
// conflict-free LDS, software-pipelined K/V staging, pf hoisted out of the
// PV d-loop. Proven: 166 us, 56 VGPR, 0 conflicts, no spill.
// Tripwire: WRITE_SIZE must stay ~17408 KB; any jump = spills -> revert.
// ---------------------------------------------------------------------------
__global__ __launch_bounds__(512, 4)
void flash_ctx(const u16t* __restrict__ Qw, const u16t* __restrict__ Kw,
               const u16t* __restrict__ VTw, const int* __restrict__ mask,
               u16t* __restrict__ ctx, float* __restrict__ mo, float* __restrict__ lo)
{
  __shared__ __attribute__((aligned(16))) u16t Kt[64 * 64];
  __shared__ __attribute__((aligned(16))) u16t Vt[64 * 64];
  __shared__ __attribute__((aligned(16))) u16t Pt[8 * 16 * 64];
  __shared__ float biasl[NS];

  const int tid  = threadIdx.x;
  const int w    = tid >> 6;
  const int lane = tid & 63;
  const int quad = lane >> 4;
  const int l16  = lane & 15;
  const int bh   = blockIdx.y;        // b*16 + h
  const int b    = bh >> 4;
  const int h    = bh & 15;
  const int qw   = blockIdx.x * 128 + w * 16;
  const int pbase = w * 1024;         // per-wave 16x64 P tile

  for (int i = tid; i < NS; i += 512)
    biasl[i] = mask[b * NS + i] ? 0.f : NEGINF;

  // preload this wave's Q fragments (16 rows x 64 d) into registers
  bf16x8 qf[2];
#pragma unroll
  for (int kk = 0; kk < 2; kk++)
    qf[kk] = *(const bf16x8*)(Qw + ((long)bh * NS + qw + l16) * NDK + kk * 32 + quad * 8);

  const f32x4 fz = {0.f, 0.f, 0.f, 0.f};
  const f32x4 fm = {NEGINF, NEGINF, NEGINF, NEGINF};
  f32x4 cacc[4];
#pragma unroll
  for (int d = 0; d < 4; d++) cacc[d] = fz;
  f32x4 mrun = fm;
  f32x4 lrun = fz;

  // staging chunk map: chunk c (0..511) -> row c>>3 (0..63), colgrp (c&7)*8
  const int kr0 = tid >> 3, kc0 = (tid & 7) * 8;
  const long kbase = (long)bh * NS;
  const long vbase = (long)bh * NDK;

  bf16x8 kv = *(const bf16x8*)(Kw  + (kbase + kr0) * NDK + kc0);
  bf16x8 vv = *(const bf16x8*)(VTw + (vbase + kr0) * NS + kc0);

  for (int kb = 0; kb < NS; kb += 64) {
    __syncthreads();
    *(bf16x8*)&Kt[swz(kr0, kc0)] = kv;
    *(bf16x8*)&Vt[swz(kr0, kc0)] = vv;
    __syncthreads();
    if (kb + 64 < NS) {   // prefetch next tile; latency hides under compute
      kv = *(const bf16x8*)(Kw  + (kbase + kb + 64 + kr0) * NDK + kc0);
      vv = *(const bf16x8*)(VTw + (vbase + kr0) * NS + kb + 64 + kc0);
    }

    // S = Q K^T (rows: q, cols: key) for this wave's 16 rows
    f32x4 s[4];
#pragma unroll
    for (int c = 0; c < 4; c++) {
      f32x4 a = fz;
#pragma unroll
      for (int kk = 0; kk < 2; kk++) {
        bf16x8 kf = *(const bf16x8*)&Kt[swz(c * 16 + l16, kk * 32 + quad * 8)];
        a = __builtin_amdgcn_mfma_f32_16x16x32_bf16(qf[kk], kf, a, 0, 0, 0);
      }
      s[c] = a;
    }

#pragma unroll
    for (int c = 0; c < 4; c++) {
      const float bias_c = biasl[kb + c * 16 + l16];
#pragma unroll
      for (int r = 0; r < 4; r++)
        s[c][r] = s[c][r] * SCALE2 + bias_c;
    }

    // row max across 4 col-frags then DPP rotate-reduce over the 16 lanes
    f32x4 mx = s[0];
#pragma unroll
    for (int c = 1; c < 4; c++)
#pragma unroll
      for (int r = 0; r < 4; r++) mx[r] = fmaxf(mx[r], s[c][r]);
#pragma unroll
    for (int r = 0; r < 4; r++) {
      float x = mx[r];
      x = fmaxf(x, ROR16(x, 1));
      x = fmaxf(x, ROR16(x, 2));
      x = fmaxf(x, ROR16(x, 4));
      x = fmaxf(x, ROR16(x, 8));
      mx[r] = x;
    }

    f32x4 alpha;
#pragma unroll
    for (int r = 0; r < 4; r++) {
      float mnew = fmaxf(mrun[r], mx[r]);
      alpha[r] = fexp2(mrun[r] - mnew);
      mrun[r] = mnew;
    }
#pragma unroll
    for (int c = 0; c < 4; c++)
#pragma unroll
      for (int r = 0; r < 4; r++) s[c][r] = fexp2(s[c][r] - mrun[r]);

    f32x4 sm = fz;
#pragma unroll
    for (int c = 0; c < 4; c++)
#pragma unroll
      for (int r = 0; r < 4; r++) sm[r] += s[c][r];
#pragma unroll
    for (int r = 0; r < 4; r++) {
      float x = sm[r];
      x += ROR16(x, 1);
      x += ROR16(x, 2);
      x += ROR16(x, 4);
      x += ROR16(x, 8);
      sm[r] = x;
    }
#pragma unroll
    for (int r = 0; r < 4; r++) lrun[r] = lrun[r] * alpha[r] + sm[r];
#pragma unroll
    for (int d = 0; d < 4; d++)
#pragma unroll
      for (int r = 0; r < 4; r++) cacc[d][r] *= alpha[r];

    // P -> LDS (A-operand layout: [q][key] row-major, swizzled)
#pragma unroll
    for (int c = 0; c < 4; c++)
#pragma unroll
      for (int r = 0; r < 4; r++)
        Pt[pbase + swz(quad * 4 + r, c * 16 + l16)] = f2bf(s[c][r]);

    // context += P * V  (per-wave Pt; same-wave DS ops are in order)
    bf16x8 pf[2];
#pragma unroll
    for (int kk = 0; kk < 2; kk++)
      pf[kk] = *(const bf16x8*)&Pt[pbase + swz(l16, kk * 32 + quad * 8)];
#pragma unroll
    for (int d = 0; d < 4; d++)
#pragma unroll
      for (int kk = 0; kk < 2; kk++) {
        bf16x8 vf = *(const bf16x8*)&Vt[swz(d * 16 + l16, kk * 32 + quad * 8)];
        cacc[d] = __builtin_amdgcn_mfma_f32_16x16x32_bf16(pf[kk], vf, cacc[d], 0, 0, 0);
      }
  }

  // epilogue: normalize, write context and (m,l)
  {
    f32x4 rinv;
#pragma unroll
    for (int r = 0; r < 4; r++) rinv[r] = 1.f / lrun[r];
#pragma unroll
    for (int d = 0; d < 4; d++)
#pragma unroll
      for (int r = 0; r < 4; r++) {
        int qg = qw + quad * 4 + r;
        int e  = h * NDK + d * 16 + l16;
        ctx[((long)(b * NS + qg)) * ND + e] = f2bf(cacc[d][r] * rinv[r]);
      }
    if (l16 == 0) {
#pragma unroll
      for (int r = 0; r < 4; r++) {
        int qg = qw + quad * 4 + r;
        mo[(long)bh * NS + qg] = mrun[r];
        lo[(long)bh * NS + qg] = lrun[r];
      }
    }
  }
}

// ---------------------------------------------------------------------------
// probs_mean: per (b, 128x128 score tile), loop all 16 heads recomputing
// S = Q K^T, p = exp2(s*SCALE2 + maskbias - m)/l, accumulate mean, fp32 out.
// Swizzled [128][64] tiles; full ml/li preload (R6 form). ml/li hoisted into
// registers per-i (they depend only on (i,r), not j): removes 4x-redundant
// scalar ds_read_b32 from the inner loop (128 -> 32 per head per thread).
// Software-pipelined head staging.
// ---------------------------------------------------------------------------
__global__ __launch_bounds__(256, 3)
void probs_mean(const u16t* __restrict__ Qw, const u16t* __restrict__ Kw,
                const int* __restrict__ mask, const float* __restrict__ mo,
                const float* __restrict__ lo, float* __restrict__ outp)
{
  __shared__ __attribute__((aligned(16))) u16t Qt[128 * 64];
  __shared__ __attribute__((aligned(16))) u16t Kt2[128 * 64];
  __shared__ float ml[NH * 128];
  __shared__ float li[NH * 128];
  __shared__ float biasl[128];

  const int tid  = threadIdx.x;
  const int w    = tid >> 6;
  const int lane = tid & 63;
  const int quad = lane >> 4;
  const int l16  = lane & 15;
  const int wm   = w >> 1, wn = w & 1;
  const int b  = blockIdx.z;
  const int q0 = blockIdx.y * 128;
  const int k0 = blockIdx.x * 128;

  for (int i = tid; i < NH * 128; i += 256) {
    int hh = i >> 7, r = i & 127;
    ml[i] = mo[((long)(b * NH + hh)) * NS + q0 + r];
    li[i] = 1.f / lo[((long)(b * NH + hh)) * NS + q0 + r];
  }
  for (int i = tid; i < 128; i += 256)
    biasl[i] = mask[b * NS + k0 + i] ? 0.f : NEGINF;

  const f32x4 fz = {0.f, 0.f, 0.f, 0.f};
  f32x4 acc[4][4];
#pragma unroll
  for (int i = 0; i < 4; i++)
#pragma unroll
    for (int j = 0; j < 4; j++) acc[i][j] = fz;

  bf16x8 qv[4], kv[4];
#pragma unroll
  for (int rr = 0; rr < 4; rr++) {
    int idx = rr * 256 + tid;
    int row = idx >> 3, off = (idx & 7) * 8;
    qv[rr] = *(const bf16x8*)(Qw + ((long)(b * NH) * NS + q0 + row) * NDK + off);
    kv[rr] = *(const bf16x8*)(Kw + ((long)(b * NH) * NS + k0 + row) * NDK + off);
  }

  for (int hh = 0; hh < NH; hh++) {
    __syncthreads();
#pragma unroll
    for (int rr = 0; rr < 4; rr++) {
      int idx = rr * 256 + tid;
      int row = idx >> 3, off = (idx & 7) * 8;
      *(bf16x8*)&Qt[swz(row, off)]  = qv[rr];
      *(bf16x8*)&Kt2[swz(row, off)] = kv[rr];
    }
    __syncthreads();
    if (hh + 1 < NH) {
#pragma unroll
      for (int rr = 0; rr < 4; rr++) {
        int idx = rr * 256 + tid;
        int row = idx >> 3, off = (idx & 7) * 8;
        qv[rr] = *(const bf16x8*)(Qw + ((long)(b * NH + hh + 1) * NS + q0 + row) * NDK + off);
        kv[rr] = *(const bf16x8*)(Kw + ((long)(b * NH + hh + 1) * NS + k0 + row) * NDK + off);
      }
    }

    bf16x8 af[4][2], bfv[4][2];
#pragma unroll
    for (int i = 0; i < 4; i++)
#pragma unroll
      for (int kk = 0; kk < 2; kk++) {
        af[i][kk]  = *(const bf16x8*)&Qt[swz(wm * 64 + i * 16 + l16, kk * 32 + quad * 8)];
        bfv[i][kk] = *(const bf16x8*)&Kt2[swz(wn * 64 + i * 16 + l16, kk * 32 + quad * 8)];
      }
#pragma unroll
    for (int i = 0; i < 4; i++) {
      // hoist ml/li for this i (depends on (i,r) only; 16-lane broadcast reads)
      float mlv[4], liv[4];
#pragma unroll
      for (int r = 0; r < 4; r++) {
        int rowb = wm * 64 + i * 16 + quad * 4 + r;
        mlv[r] = ml[hh * 128 + rowb];
        liv[r] = li[hh * 128 + rowb];
      }
#pragma unroll
      for (int j = 0; j < 4; j++) {
        f32x4 s = fz;
#pragma unroll
        for (int kk = 0; kk < 2; kk++)
          s = __builtin_amdgcn_mfma_f32_16x16x32_bf16(af[i][kk], bfv[j][kk], s, 0, 0, 0);
        const float bias_c = biasl[wn * 64 + j * 16 + l16];
#pragma unroll
        for (int r = 0; r < 4; r++) {
          float p = fexp2(s[r] * SCALE2 + bias_c - mlv[r]) * liv[r];
          acc[i][j][r] += p;
        }
      }
    }
  }

#pragma unroll
  for (int i = 0; i < 4; i++)
#pragma unroll
    for (int j = 0; j < 4; j++)
#pragma unroll
      for (int r = 0; r < 4; r++) {
        int row = q0 + wm * 64 + i * 16 + quad * 4 + r;
        int col = k0 + wn * 64 + j * 16 + l16;
        outp[((long)(b * NS + row)) * NS + col] = acc[i][j][r] * (1.f / 16.f);
      }
}

// ---------------------------------------------------------------------------
extern "C" void kernel_launch(void* const* d_in, const int* in_sizes, int n_in,
                              void* d_out, int out_size, void* d_ws, size_t ws_size,
                              hipStream_t stream)
{
  (void)in_sizes; (void)n_in; (void)out_size; (void)ws_size;
  const float* query = (const float*)d_in[0];
  const float* keyt  = (const float*)d_in[1];
  const float* value = (const float*)d_in[2];
  const int*   mask  = (const int*)d_in[3];
  const float* Wq = (const float*)d_in[4];
  const float* Wk = (const float*)d_in[5];
  const float* Wv = (const float*)d_in[6];
  const float* Wo = (const float*)d_in[7];
  const float* bo = (const float*)d_in[8];

  float* out  = (float*)d_out;                     // [B,S,D] fp32
  float* outp = out + (long)NB * NS * ND;          // [B,S,S] fp32

  u16t* q_ws  = (u16t*)d_ws;                       // [B,H,S,dk] bf16
  u16t* k_ws  = q_ws + (long)NB * NH * NS * NDK;   // [B,H,S,dk] bf16
  u16t* vt_ws = k_ws + (long)NB * NH * NS * NDK;   // [B,H,dk,S] bf16
  float* m_ws = (float*)(vt_ws + (long)NB * NH * NS * NDK);
  float* l_ws = m_ws + (long)NB * NH * NS;
  // ctx scratch (bf16) lives in the outp region of d_out; it is fully
  // consumed by the output GEMM before probs_mean overwrites the region.
  u16t* ctx_ws = (u16t*)outp;

  dim3 blk(256);
  gemm_nt<float, 1><<<dim3(64, 8), blk, 0, stream>>>(query, Wq, q_ws, nullptr);
  gemm_nt<float, 1><<<dim3(64, 8), blk, 0, stream>>>(keyt,  Wk, k_ws, nullptr);
  gemm_nt<float, 2><<<dim3(64, 8), blk, 0, stream>>>(value, Wv, vt_ws, nullptr);
  flash_ctx<<<dim3(NS / 128, NB * NH), dim3(512), 0, stream>>>(q_ws, k_ws, vt_ws, mask,
                                                               ctx_ws, m_ws, l_ws);
  gemm_nt<u16t, 0><<<dim3(64, 8), blk, 0, stream>>>(ctx_ws, Wo, out, bo);
  probs_mean<<<dim3(NS / 128, NS / 128, NB), blk, 0, stream>>>(q_ws, k_ws, mask,
                                                               m_ws, l_ws, outp);
}